// Round 4
// baseline (695.274 us; speedup 1.0000x reference)
//
#include <hip/hip_runtime.h>
#include <hip/hip_bf16.h>

#define N_NODES 100000
#define N_EDGES 600000
#define NB      512
#define H       128
#define ED      8
#define SCAN_CHUNK 1024
#define N_CHUNKS   98   // 98*1024 = 100352 >= N_NODES+1

typedef __attribute__((ext_vector_type(8))) short short8;
typedef __attribute__((ext_vector_type(4))) float f32x4;
typedef unsigned short u16;
typedef unsigned int   u32;

static __device__ __forceinline__ u16 f2bf(float f) {
    u32 u = __float_as_uint(f);
    u32 r = u + 0x7fffu + ((u >> 16) & 1u);
    return (u16)(r >> 16);
}
static __device__ __forceinline__ float bf2f(u32 h) {
    return __uint_as_float(h << 16);
}

// ---- weight pack: per-lane B-fragment order for mfma_f32_16x16x32_bf16 ----
__global__ __launch_bounds__(256) void pack_weights_kernel(
    const float* __restrict__ W, int Krows, int kkmax, short8* __restrict__ out)
{
    int slot = blockIdx.x * 256 + threadIdx.x;
    int total = 4 * kkmax * 2 * 64;
    if (slot >= total) return;
    int lane = slot & 63;
    int t = slot >> 6;
    int nt = t & 1; t >>= 1;
    int kk = t % kkmax;
    int w  = t / kkmax;
    int quad = lane >> 4, n15 = lane & 15;
    int n = w * 32 + nt * 16 + n15;
    short8 v;
    #pragma unroll
    for (int j = 0; j < 8; j++) {
        int k = kk * 32 + quad * 8 + j;
        v[j] = (k < Krows) ? (short)f2bf(W[k * H + n]) : (short)0;
    }
    out[slot] = v;
}

// ---------------- CSR build ------------------------------------------------
__global__ __launch_bounds__(256) void hist_kernel(
    const int* __restrict__ edge_index, int* __restrict__ counts)
{
    int e = blockIdx.x * 256 + threadIdx.x;
    if (e < N_EDGES) atomicAdd(&counts[edge_index[N_EDGES + e]], 1);
}

__global__ __launch_bounds__(SCAN_CHUNK) void scan1_kernel(
    const int* __restrict__ counts, int* __restrict__ chunk_scan,
    int* __restrict__ bsum_raw)
{
    __shared__ int s[SCAN_CHUNK];
    int tid = threadIdx.x;
    int gid = blockIdx.x * SCAN_CHUNK + tid;
    int v = counts[gid];
    s[tid] = v;
    __syncthreads();
    #pragma unroll
    for (int off = 1; off < SCAN_CHUNK; off <<= 1) {
        int t = (tid >= off) ? s[tid - off] : 0;
        __syncthreads();
        s[tid] += t;
        __syncthreads();
    }
    chunk_scan[gid] = s[tid] - v;
    if (tid == SCAN_CHUNK - 1) bsum_raw[blockIdx.x] = s[tid];
}

__global__ __launch_bounds__(128) void scan2_kernel(
    const int* __restrict__ bsum_raw, int* __restrict__ bsum_scan)
{
    __shared__ int s[128];
    int tid = threadIdx.x;
    int v = (tid < N_CHUNKS) ? bsum_raw[tid] : 0;
    s[tid] = v;
    __syncthreads();
    #pragma unroll
    for (int off = 1; off < 128; off <<= 1) {
        int t = (tid >= off) ? s[tid - off] : 0;
        __syncthreads();
        s[tid] += t;
        __syncthreads();
    }
    bsum_scan[tid] = s[tid] - v;
}

// fill: src_list[pos]=src (CSR order), pos_of[e]=pos (for edge_mlp scatter)
__global__ __launch_bounds__(256) void fill_kernel(
    const int* __restrict__ edge_index,
    const int* __restrict__ chunk_scan, const int* __restrict__ bsum_scan,
    int* __restrict__ counts, int* __restrict__ src_list,
    int* __restrict__ pos_of)
{
    int e = blockIdx.x * 256 + threadIdx.x;
    if (e >= N_EDGES) return;
    int src = edge_index[e];
    int dst = edge_index[N_EDGES + e];
    int slot = atomicAdd(&counts[dst], -1) - 1;
    int pos = chunk_scan[dst] + bsum_scan[dst >> 10] + slot;
    src_list[pos] = src;
    pos_of[e] = pos;
}

// ---------------- node MLP (MFMA layer2): x bf16 [N,H] ---------------------
__global__ __launch_bounds__(256) void node_mlp_mfma(
    const int* __restrict__ ids,
    const float* __restrict__ w1, const float* __restrict__ b1,
    const short8* __restrict__ pW2, const float* __restrict__ b2,
    u16* __restrict__ x_out)
{
    __shared__ u16 sH[64 * 136];
    __shared__ float s_x0[64];
    int tid = threadIdx.x;
    int w = tid >> 6, lane = tid & 63, quad = lane >> 4, n15 = lane & 15;
    short8 fW2[4][2];
    #pragma unroll
    for (int kk = 0; kk < 4; kk++) {
        fW2[kk][0] = pW2[((w * 4 + kk) * 2 + 0) * 64 + lane];
        fW2[kk][1] = pW2[((w * 4 + kk) * 2 + 1) * 64 + lane];
    }
    float rb2[2] = { b2[w * 32 + n15], b2[w * 32 + 16 + n15] };
    float w1c = w1[tid & 127], b1c = b1[tid & 127];
    const int ntile = (N_NODES + 63) / 64;
    for (int tile = blockIdx.x; tile < ntile; tile += gridDim.x) {
        int row0 = tile * 64;
        if (tid < 64) {
            int n = row0 + tid;
            float x0 = (n < N_NODES) ? (float)ids[n] / 281474976710655.0f : 0.0f;
            s_x0[tid] = fminf(fmaxf(x0, 0.0f), 1.0f);
        }
        __syncthreads();
        int half = tid >> 7, c = tid & 127;
        #pragma unroll 8
        for (int rr = 0; rr < 32; rr++) {
            int r = half + rr * 2;
            sH[r * 136 + c] = f2bf(fmaxf(s_x0[r] * w1c + b1c, 0.0f));
        }
        __syncthreads();
        f32x4 acc[4][2];
        #pragma unroll
        for (int s = 0; s < 4; s++) { acc[s][0] = (f32x4){0,0,0,0}; acc[s][1] = (f32x4){0,0,0,0}; }
        #pragma unroll
        for (int kk = 0; kk < 4; kk++) {
            #pragma unroll
            for (int s = 0; s < 4; s++) {
                short8 a = *(const short8*)&sH[(s * 16 + n15) * 136 + kk * 32 + quad * 8];
                acc[s][0] = __builtin_amdgcn_mfma_f32_16x16x32_bf16(a, fW2[kk][0], acc[s][0], 0, 0, 0);
                acc[s][1] = __builtin_amdgcn_mfma_f32_16x16x32_bf16(a, fW2[kk][1], acc[s][1], 0, 0, 0);
            }
        }
        #pragma unroll
        for (int s = 0; s < 4; s++)
            #pragma unroll
            for (int nt = 0; nt < 2; nt++) {
                int col = w * 32 + nt * 16 + n15;
                #pragma unroll
                for (int reg = 0; reg < 4; reg++) {
                    int n = row0 + s * 16 + quad * 4 + reg;
                    if (n < N_NODES)
                        x_out[(long)n * H + col] = f2bf(acc[s][nt][reg] + rb2[nt]);
                }
            }
        __syncthreads();
    }
}

// ---------------- edge MLP (MFMA): writes e in CSR-permuted order ----------
__global__ __launch_bounds__(256) void edge_mlp_mfma(
    const float* __restrict__ attr,
    const int* __restrict__ pos_of,
    const short8* __restrict__ pW1, const float* __restrict__ b1,
    const short8* __restrict__ pW2, const float* __restrict__ b2,
    u16* __restrict__ e_perm)
{
    __shared__ u16 sA[64 * 40];
    __shared__ u16 sH[64 * 136];
    __shared__ int sPos[64];
    int tid = threadIdx.x;
    int w = tid >> 6, lane = tid & 63, quad = lane >> 4, n15 = lane & 15;
    short8 fW1[2];
    fW1[0] = pW1[(w * 2 + 0) * 64 + lane];
    fW1[1] = pW1[(w * 2 + 1) * 64 + lane];
    short8 fW2[4][2];
    #pragma unroll
    for (int kk = 0; kk < 4; kk++) {
        fW2[kk][0] = pW2[((w * 4 + kk) * 2 + 0) * 64 + lane];
        fW2[kk][1] = pW2[((w * 4 + kk) * 2 + 1) * 64 + lane];
    }
    float rb1[2] = { b1[w * 32 + n15], b1[w * 32 + 16 + n15] };
    float rb2[2] = { b2[w * 32 + n15], b2[w * 32 + 16 + n15] };
    const int ntile = N_EDGES / 64;   // 9375 exact
    for (int tile = blockIdx.x; tile < ntile; tile += gridDim.x) {
        int row0 = tile * 64;
        if (tid < 64) sPos[tid] = pos_of[row0 + tid];
        if (tid >= 64 && tid < 192) {
            int t2 = tid - 64;
            int r = t2 >> 1, c4 = (t2 & 1) * 4;
            float4 v = *(const float4*)&attr[(long)(row0 + r) * ED + c4];
            ushort4 o;
            o.x = f2bf(v.x); o.y = f2bf(v.y); o.z = f2bf(v.z); o.w = f2bf(v.w);
            *(ushort4*)&sA[r * 40 + c4] = o;
        } else if (tid >= 192) {
            int idx = tid - 192;   // zero-fill k=8..31 : 64 rows * 3 chunks of 8
            for (; idx < 192; idx += 64) {
                int r = idx / 3, c8 = 8 + (idx % 3) * 8;
                *(uint4*)&sA[r * 40 + c8] = make_uint4(0, 0, 0, 0);
            }
        }
        __syncthreads();
        // GEMM1 (K=32, one step)
        f32x4 acc[4][2];
        #pragma unroll
        for (int s = 0; s < 4; s++) { acc[s][0] = (f32x4){0,0,0,0}; acc[s][1] = (f32x4){0,0,0,0}; }
        #pragma unroll
        for (int s = 0; s < 4; s++) {
            short8 a = *(const short8*)&sA[(s * 16 + n15) * 40 + quad * 8];
            acc[s][0] = __builtin_amdgcn_mfma_f32_16x16x32_bf16(a, fW1[0], acc[s][0], 0, 0, 0);
            acc[s][1] = __builtin_amdgcn_mfma_f32_16x16x32_bf16(a, fW1[1], acc[s][1], 0, 0, 0);
        }
        #pragma unroll
        for (int s = 0; s < 4; s++)
            #pragma unroll
            for (int nt = 0; nt < 2; nt++) {
                int col = w * 32 + nt * 16 + n15;
                #pragma unroll
                for (int reg = 0; reg < 4; reg++)
                    sH[(s * 16 + quad * 4 + reg) * 136 + col] =
                        f2bf(fmaxf(acc[s][nt][reg] + rb1[nt], 0.0f));
            }
        __syncthreads();
        // GEMM2 (K=128)
        #pragma unroll
        for (int s = 0; s < 4; s++) { acc[s][0] = (f32x4){0,0,0,0}; acc[s][1] = (f32x4){0,0,0,0}; }
        #pragma unroll
        for (int kk = 0; kk < 4; kk++) {
            #pragma unroll
            for (int s = 0; s < 4; s++) {
                short8 a = *(const short8*)&sH[(s * 16 + n15) * 136 + kk * 32 + quad * 8];
                acc[s][0] = __builtin_amdgcn_mfma_f32_16x16x32_bf16(a, fW2[kk][0], acc[s][0], 0, 0, 0);
                acc[s][1] = __builtin_amdgcn_mfma_f32_16x16x32_bf16(a, fW2[kk][1], acc[s][1], 0, 0, 0);
            }
        }
        #pragma unroll
        for (int s = 0; s < 4; s++)
            #pragma unroll
            for (int nt = 0; nt < 2; nt++) {
                int col = w * 32 + nt * 16 + n15;
                #pragma unroll
                for (int reg = 0; reg < 4; reg++) {
                    long r = sPos[s * 16 + quad * 4 + reg];
                    e_perm[r * H + col] = f2bf(acc[s][nt][reg] + rb2[nt]);
                }
            }
        __syncthreads();
    }
}

// ------- fused aggregate + conv MLP: x_out = mlp(x + sum relu(x[src]+e)) ---
__global__ __launch_bounds__(256) void conv_fused_mfma(
    const int* __restrict__ src_list,
    const int* __restrict__ chunk_scan, const int* __restrict__ bsum_scan,
    const u16* __restrict__ e_perm,
    const u16* __restrict__ x,
    const short8* __restrict__ pW1, const float* __restrict__ b1,
    const short8* __restrict__ pW2, const float* __restrict__ b2,
    u16* __restrict__ x_out)
{
    __shared__ u16 sA[64 * 136];
    __shared__ u16 sH[64 * 136];
    int tid = threadIdx.x;
    int w = tid >> 6, lane = tid & 63, quad = lane >> 4, n15 = lane & 15;
    short8 fW1[4][2], fW2[4][2];
    #pragma unroll
    for (int kk = 0; kk < 4; kk++) {
        fW1[kk][0] = pW1[((w * 4 + kk) * 2 + 0) * 64 + lane];
        fW1[kk][1] = pW1[((w * 4 + kk) * 2 + 1) * 64 + lane];
        fW2[kk][0] = pW2[((w * 4 + kk) * 2 + 0) * 64 + lane];
        fW2[kk][1] = pW2[((w * 4 + kk) * 2 + 1) * 64 + lane];
    }
    float rb1[2] = { b1[w * 32 + n15], b1[w * 32 + 16 + n15] };
    float rb2[2] = { b2[w * 32 + n15], b2[w * 32 + 16 + n15] };
    const int fo = lane * 2;
    const int ntile = (N_NODES + 63) / 64;
    for (int tile = blockIdx.x; tile < ntile; tile += gridDim.x) {
        int row0 = tile * 64;
        // ---- aggregation phase: wave w owns rows w, w+4, ... (16 rows) ----
        for (int r = w; r < 64; r += 4) {
            int n = row0 + r;
            float a0 = 0.0f, a1 = 0.0f;
            if (n < N_NODES) {
                int beg = chunk_scan[n]     + bsum_scan[n >> 10];
                int end = chunk_scan[n + 1] + bsum_scan[(n + 1) >> 10];
                for (int j0 = beg; j0 < end; j0 += 64) {
                    int m = min(64, end - j0);
                    int sv = (lane < m) ? src_list[j0 + lane] : 0;
                    for (int j = 0; j < m; j++) {
                        int src = __shfl(sv, j);
                        u32 xv = *(const u32*)&x[(long)src * H + fo];
                        u32 ev = *(const u32*)&e_perm[(long)(j0 + j) * H + fo];
                        a0 += fmaxf(bf2f(xv & 0xffff) + bf2f(ev & 0xffff), 0.0f);
                        a1 += fmaxf(bf2f(xv >> 16)    + bf2f(ev >> 16),    0.0f);
                    }
                }
                u32 xself = *(const u32*)&x[(long)n * H + fo];
                a0 += bf2f(xself & 0xffff);
                a1 += bf2f(xself >> 16);
            }
            *(u32*)&sA[r * 136 + fo] = (u32)f2bf(a0) | ((u32)f2bf(a1) << 16);
        }
        __syncthreads();
        // ---- GEMM1 ----
        f32x4 acc[4][2];
        #pragma unroll
        for (int s = 0; s < 4; s++) { acc[s][0] = (f32x4){0,0,0,0}; acc[s][1] = (f32x4){0,0,0,0}; }
        #pragma unroll
        for (int kk = 0; kk < 4; kk++) {
            #pragma unroll
            for (int s = 0; s < 4; s++) {
                short8 a = *(const short8*)&sA[(s * 16 + n15) * 136 + kk * 32 + quad * 8];
                acc[s][0] = __builtin_amdgcn_mfma_f32_16x16x32_bf16(a, fW1[kk][0], acc[s][0], 0, 0, 0);
                acc[s][1] = __builtin_amdgcn_mfma_f32_16x16x32_bf16(a, fW1[kk][1], acc[s][1], 0, 0, 0);
            }
        }
        #pragma unroll
        for (int s = 0; s < 4; s++)
            #pragma unroll
            for (int nt = 0; nt < 2; nt++) {
                int col = w * 32 + nt * 16 + n15;
                #pragma unroll
                for (int reg = 0; reg < 4; reg++)
                    sH[(s * 16 + quad * 4 + reg) * 136 + col] =
                        f2bf(fmaxf(acc[s][nt][reg] + rb1[nt], 0.0f));
            }
        __syncthreads();
        // ---- GEMM2 ----
        #pragma unroll
        for (int s = 0; s < 4; s++) { acc[s][0] = (f32x4){0,0,0,0}; acc[s][1] = (f32x4){0,0,0,0}; }
        #pragma unroll
        for (int kk = 0; kk < 4; kk++) {
            #pragma unroll
            for (int s = 0; s < 4; s++) {
                short8 a = *(const short8*)&sH[(s * 16 + n15) * 136 + kk * 32 + quad * 8];
                acc[s][0] = __builtin_amdgcn_mfma_f32_16x16x32_bf16(a, fW2[kk][0], acc[s][0], 0, 0, 0);
                acc[s][1] = __builtin_amdgcn_mfma_f32_16x16x32_bf16(a, fW2[kk][1], acc[s][1], 0, 0, 0);
            }
        }
        #pragma unroll
        for (int s = 0; s < 4; s++)
            #pragma unroll
            for (int nt = 0; nt < 2; nt++) {
                int col = w * 32 + nt * 16 + n15;
                #pragma unroll
                for (int reg = 0; reg < 4; reg++) {
                    int n = row0 + s * 16 + quad * 4 + reg;
                    if (n < N_NODES)
                        x_out[(long)n * H + col] = f2bf(fmaxf(acc[s][nt][reg] + rb2[nt], 0.0f));
                }
            }
        __syncthreads();
    }
}

// ---------------- mean-pool (sorted batch, segment flush) ------------------
__global__ __launch_bounds__(128) void pool_kernel(
    const u16* __restrict__ x, const int* __restrict__ batch,
    float* __restrict__ sums, float* __restrict__ cnt)
{
    int j = threadIdx.x;
    const int nper = (N_NODES + gridDim.x - 1) / gridDim.x;
    int n0 = blockIdx.x * nper;
    int n1 = min(n0 + nper, N_NODES);
    if (n0 >= n1) return;
    int cur = -1;
    float acc = 0.0f, cacc = 0.0f;
    for (int n = n0; n < n1; n++) {
        int b = batch[n];
        if (b != cur) {
            if (cur >= 0) {
                atomicAdd(&sums[cur * H + j], acc);
                if (j == 0) atomicAdd(&cnt[cur], cacc);
            }
            acc = 0.0f; cacc = 0.0f; cur = b;
        }
        acc += bf2f(x[(long)n * H + j]);
        cacc += 1.0f;
    }
    if (cur >= 0) {
        atomicAdd(&sums[cur * H + j], acc);
        if (j == 0) atomicAdd(&cnt[cur], cacc);
    }
}

// ---------------- regressor ------------------------------------------------
__global__ __launch_bounds__(128) void regressor_kernel(
    const float* __restrict__ sums, const float* __restrict__ cnt,
    const float* __restrict__ depth,
    const float* __restrict__ w1, const float* __restrict__ b1,
    const float* __restrict__ w2, const float* __restrict__ b2,
    float* __restrict__ out)
{
    __shared__ float s_mean[H];
    __shared__ float s_red[2];
    int b = blockIdx.x;
    int j = threadIdx.x;
    float c = fmaxf(cnt[b], 1.0f);
    s_mean[j] = sums[b * H + j] / c;
    __syncthreads();
    float h = b1[j];
    #pragma unroll 8
    for (int k = 0; k < H; k++) h += s_mean[k] * w1[k * H + j];
    h += depth[b] * w1[H * H + j];
    h = fmaxf(h, 0.0f);
    float p = h * w2[j];
    #pragma unroll
    for (int off = 32; off >= 1; off >>= 1) p += __shfl_down(p, off, 64);
    if ((j & 63) == 0) s_red[j >> 6] = p;
    __syncthreads();
    if (j == 0) out[b] = s_red[0] + s_red[1] + b2[0];
}

extern "C" void kernel_launch(void* const* d_in, const int* in_sizes, int n_in,
                              void* d_out, int out_size, void* d_ws, size_t ws_size,
                              hipStream_t stream)
{
    const int*   ids   = (const int*)  d_in[0];
    const int*   eidx  = (const int*)  d_in[1];
    const float* eattr = (const float*)d_in[2];
    const int*   batch = (const int*)  d_in[3];
    const float* depth = (const float*)d_in[4];
    const float* id_w1 = (const float*)d_in[5];
    const float* id_b1 = (const float*)d_in[6];
    const float* id_w2 = (const float*)d_in[7];
    const float* id_b2 = (const float*)d_in[8];
    const float* ed_w1 = (const float*)d_in[9];
    const float* ed_b1 = (const float*)d_in[10];
    const float* ed_w2 = (const float*)d_in[11];
    const float* ed_b2 = (const float*)d_in[12];
    const float* c1_w1 = (const float*)d_in[13];
    const float* c1_b1 = (const float*)d_in[14];
    const float* c1_w2 = (const float*)d_in[15];
    const float* c1_b2 = (const float*)d_in[16];
    const float* c2_w1 = (const float*)d_in[17];
    const float* c2_b1 = (const float*)d_in[18];
    const float* c2_w2 = (const float*)d_in[19];
    const float* c2_b2 = (const float*)d_in[20];
    const float* rg_w1 = (const float*)d_in[21];
    const float* rg_b1 = (const float*)d_in[22];
    const float* rg_w2 = (const float*)d_in[23];
    const float* rg_b2 = (const float*)d_in[24];

    char* ws = (char*)d_ws;
    u16*   e_buf    = (u16*)  (ws);                      // 153,600,000 B (CSR order)
    u16*   x_buf    = (u16*)  (ws + 153600000);          //  25,600,000 B
    u16*   y_buf    = (u16*)  (ws + 179200000);          //  25,600,000 B
    float* sums_buf = (float*)(ws + 204800000);          //     262,144 B
    float* cnt_buf  = (float*)(ws + 205062144);          //       2,048 B
    int*   counts   = (int*)  (ws + 205064192);          //     401,408 B
    int*   chunk_sc = (int*)  (ws + 205465600);          //     401,408 B
    int*   bsum_raw = (int*)  (ws + 205867008);          //         512 B
    int*   bsum_sc  = (int*)  (ws + 205867520);          //         512 B
    int*   src_list = (int*)  (ws + 205868032);          //   2,400,000 B
    int*   pos_of   = (int*)  (ws + 208268032);          //   2,400,000 B
    short8* ed_w1p  = (short8*)(ws + 210668032);         //       8,192 B
    short8* ed_w2p  = (short8*)(ws + 210676224);         //      32,768 B
    short8* c1_w1p  = (short8*)(ws + 210708992);
    short8* c1_w2p  = (short8*)(ws + 210741760);
    short8* c2_w1p  = (short8*)(ws + 210774528);
    short8* c2_w2p  = (short8*)(ws + 210807296);
    short8* id_w2p  = (short8*)(ws + 210840064);

    // weight packs (tiny)
    pack_weights_kernel<<<2, 256, 0, stream>>>(ed_w1, ED, 1, ed_w1p);
    pack_weights_kernel<<<8, 256, 0, stream>>>(ed_w2, H, 4, ed_w2p);
    pack_weights_kernel<<<8, 256, 0, stream>>>(c1_w1, H, 4, c1_w1p);
    pack_weights_kernel<<<8, 256, 0, stream>>>(c1_w2, H, 4, c1_w2p);
    pack_weights_kernel<<<8, 256, 0, stream>>>(c2_w1, H, 4, c2_w1p);
    pack_weights_kernel<<<8, 256, 0, stream>>>(c2_w2, H, 4, c2_w2p);
    pack_weights_kernel<<<8, 256, 0, stream>>>(id_w2, H, 4, id_w2p);

    // CSR build first (edge_mlp needs pos_of)
    hipMemsetAsync(counts, 0, 401408, stream);
    hist_kernel <<<(N_EDGES + 255) / 256, 256, 0, stream>>>(eidx, counts);
    scan1_kernel<<<N_CHUNKS, SCAN_CHUNK, 0, stream>>>(counts, chunk_sc, bsum_raw);
    scan2_kernel<<<1, 128, 0, stream>>>(bsum_raw, bsum_sc);
    fill_kernel <<<(N_EDGES + 255) / 256, 256, 0, stream>>>(eidx, chunk_sc, bsum_sc,
                                                            counts, src_list, pos_of);

    // front-end
    node_mlp_mfma<<<768, 256, 0, stream>>>(ids, id_w1, id_b1, id_w2p, id_b2, x_buf);
    edge_mlp_mfma<<<2048, 256, 0, stream>>>(eattr, pos_of, ed_w1p, ed_b1, ed_w2p, ed_b2, e_buf);

    // conv 1 (fused aggregate + MLP): x_buf -> y_buf
    conv_fused_mfma<<<1563, 256, 0, stream>>>(src_list, chunk_sc, bsum_sc, e_buf, x_buf,
                                              c1_w1p, c1_b1, c1_w2p, c1_b2, y_buf);
    // conv 2: y_buf -> x_buf
    conv_fused_mfma<<<1563, 256, 0, stream>>>(src_list, chunk_sc, bsum_sc, e_buf, y_buf,
                                              c2_w1p, c2_b1, c2_w2p, c2_b2, x_buf);

    // pooling + regressor
    hipMemsetAsync(sums_buf, 0, (size_t)(NB * H + NB) * 4, stream);
    pool_kernel<<<512, 128, 0, stream>>>(x_buf, batch, sums_buf, cnt_buf);
    regressor_kernel<<<NB, 128, 0, stream>>>(sums_buf, cnt_buf, depth,
                                             rg_w1, rg_b1, rg_w2, rg_b2, (float*)d_out);
}

// Round 5
// 506.913 us; speedup vs baseline: 1.3716x; 1.3716x over previous
//
#include <hip/hip_runtime.h>
#include <hip/hip_bf16.h>

#define N_NODES 100000
#define N_EDGES 600000
#define NB      512
#define H       128
#define ED      8
#define SCAN_CHUNK 1024
#define N_CHUNKS   98   // 98*1024 = 100352 >= N_NODES+1

typedef __attribute__((ext_vector_type(8))) short short8;
typedef __attribute__((ext_vector_type(4))) float f32x4;
typedef unsigned short u16;
typedef unsigned int   u32;

static __device__ __forceinline__ u16 f2bf(float f) {
    u32 u = __float_as_uint(f);
    u32 r = u + 0x7fffu + ((u >> 16) & 1u);
    return (u16)(r >> 16);
}
static __device__ __forceinline__ float bf2f(u32 h) {
    return __uint_as_float(h << 16);
}

// ---- weight pack: per-lane B-fragment order for mfma_f32_16x16x32_bf16 ----
__global__ __launch_bounds__(256) void pack_weights_kernel(
    const float* __restrict__ W, int Krows, int kkmax, short8* __restrict__ out)
{
    int slot = blockIdx.x * 256 + threadIdx.x;
    int total = 4 * kkmax * 2 * 64;
    if (slot >= total) return;
    int lane = slot & 63;
    int t = slot >> 6;
    int nt = t & 1; t >>= 1;
    int kk = t % kkmax;
    int w  = t / kkmax;
    int quad = lane >> 4, n15 = lane & 15;
    int n = w * 32 + nt * 16 + n15;
    short8 v;
    #pragma unroll
    for (int j = 0; j < 8; j++) {
        int k = kk * 32 + quad * 8 + j;
        v[j] = (k < Krows) ? (short)f2bf(W[k * H + n]) : (short)0;
    }
    out[slot] = v;
}

// ---------------- CSR build ------------------------------------------------
__global__ __launch_bounds__(256) void hist_kernel(
    const int* __restrict__ edge_index, int* __restrict__ counts)
{
    int e = blockIdx.x * 256 + threadIdx.x;
    if (e < N_EDGES) atomicAdd(&counts[edge_index[N_EDGES + e]], 1);
}

__global__ __launch_bounds__(SCAN_CHUNK) void scan1_kernel(
    const int* __restrict__ counts, int* __restrict__ chunk_scan,
    int* __restrict__ bsum_raw)
{
    __shared__ int s[SCAN_CHUNK];
    int tid = threadIdx.x;
    int gid = blockIdx.x * SCAN_CHUNK + tid;
    int v = counts[gid];
    s[tid] = v;
    __syncthreads();
    #pragma unroll
    for (int off = 1; off < SCAN_CHUNK; off <<= 1) {
        int t = (tid >= off) ? s[tid - off] : 0;
        __syncthreads();
        s[tid] += t;
        __syncthreads();
    }
    chunk_scan[gid] = s[tid] - v;
    if (tid == SCAN_CHUNK - 1) bsum_raw[blockIdx.x] = s[tid];
}

__global__ __launch_bounds__(128) void scan2_kernel(
    const int* __restrict__ bsum_raw, int* __restrict__ bsum_scan)
{
    __shared__ int s[128];
    int tid = threadIdx.x;
    int v = (tid < N_CHUNKS) ? bsum_raw[tid] : 0;
    s[tid] = v;
    __syncthreads();
    #pragma unroll
    for (int off = 1; off < 128; off <<= 1) {
        int t = (tid >= off) ? s[tid - off] : 0;
        __syncthreads();
        s[tid] += t;
        __syncthreads();
    }
    bsum_scan[tid] = s[tid] - v;
}

// fill: src_list[pos]=src (CSR order), pos_of[e]=pos (for edge_mlp scatter)
__global__ __launch_bounds__(256) void fill_kernel(
    const int* __restrict__ edge_index,
    const int* __restrict__ chunk_scan, const int* __restrict__ bsum_scan,
    int* __restrict__ counts, int* __restrict__ src_list,
    int* __restrict__ pos_of)
{
    int e = blockIdx.x * 256 + threadIdx.x;
    if (e >= N_EDGES) return;
    int src = edge_index[e];
    int dst = edge_index[N_EDGES + e];
    int slot = atomicAdd(&counts[dst], -1) - 1;
    int pos = chunk_scan[dst] + bsum_scan[dst >> 10] + slot;
    src_list[pos] = src;
    pos_of[e] = pos;
}

// ---------------- node MLP (MFMA layer2): x bf16 [N,H] ---------------------
__global__ __launch_bounds__(256) void node_mlp_mfma(
    const int* __restrict__ ids,
    const float* __restrict__ w1, const float* __restrict__ b1,
    const short8* __restrict__ pW2, const float* __restrict__ b2,
    u16* __restrict__ x_out)
{
    __shared__ u16 sH[64 * 136];
    __shared__ float s_x0[64];
    int tid = threadIdx.x;
    int w = tid >> 6, lane = tid & 63, quad = lane >> 4, n15 = lane & 15;
    short8 fW2[4][2];
    #pragma unroll
    for (int kk = 0; kk < 4; kk++) {
        fW2[kk][0] = pW2[((w * 4 + kk) * 2 + 0) * 64 + lane];
        fW2[kk][1] = pW2[((w * 4 + kk) * 2 + 1) * 64 + lane];
    }
    float rb2[2] = { b2[w * 32 + n15], b2[w * 32 + 16 + n15] };
    float w1c = w1[tid & 127], b1c = b1[tid & 127];
    const int ntile = (N_NODES + 63) / 64;
    for (int tile = blockIdx.x; tile < ntile; tile += gridDim.x) {
        int row0 = tile * 64;
        if (tid < 64) {
            int n = row0 + tid;
            float x0 = (n < N_NODES) ? (float)ids[n] / 281474976710655.0f : 0.0f;
            s_x0[tid] = fminf(fmaxf(x0, 0.0f), 1.0f);
        }
        __syncthreads();
        int half = tid >> 7, c = tid & 127;
        #pragma unroll 8
        for (int rr = 0; rr < 32; rr++) {
            int r = half + rr * 2;
            sH[r * 136 + c] = f2bf(fmaxf(s_x0[r] * w1c + b1c, 0.0f));
        }
        __syncthreads();
        f32x4 acc[4][2];
        #pragma unroll
        for (int s = 0; s < 4; s++) { acc[s][0] = (f32x4){0,0,0,0}; acc[s][1] = (f32x4){0,0,0,0}; }
        #pragma unroll
        for (int kk = 0; kk < 4; kk++) {
            #pragma unroll
            for (int s = 0; s < 4; s++) {
                short8 a = *(const short8*)&sH[(s * 16 + n15) * 136 + kk * 32 + quad * 8];
                acc[s][0] = __builtin_amdgcn_mfma_f32_16x16x32_bf16(a, fW2[kk][0], acc[s][0], 0, 0, 0);
                acc[s][1] = __builtin_amdgcn_mfma_f32_16x16x32_bf16(a, fW2[kk][1], acc[s][1], 0, 0, 0);
            }
        }
        #pragma unroll
        for (int s = 0; s < 4; s++)
            #pragma unroll
            for (int nt = 0; nt < 2; nt++) {
                int col = w * 32 + nt * 16 + n15;
                #pragma unroll
                for (int reg = 0; reg < 4; reg++) {
                    int n = row0 + s * 16 + quad * 4 + reg;
                    if (n < N_NODES)
                        x_out[(long)n * H + col] = f2bf(acc[s][nt][reg] + rb2[nt]);
                }
            }
        __syncthreads();
    }
}

// ---------------- edge MLP (MFMA): writes e in CSR-permuted order ----------
__global__ __launch_bounds__(256) void edge_mlp_mfma(
    const float* __restrict__ attr,
    const int* __restrict__ pos_of,
    const short8* __restrict__ pW1, const float* __restrict__ b1,
    const short8* __restrict__ pW2, const float* __restrict__ b2,
    u16* __restrict__ e_perm)
{
    __shared__ u16 sA[64 * 40];
    __shared__ u16 sH[64 * 136];
    __shared__ int sPos[64];
    int tid = threadIdx.x;
    int w = tid >> 6, lane = tid & 63, quad = lane >> 4, n15 = lane & 15;
    short8 fW1[2];
    fW1[0] = pW1[(w * 2 + 0) * 64 + lane];
    fW1[1] = pW1[(w * 2 + 1) * 64 + lane];
    short8 fW2[4][2];
    #pragma unroll
    for (int kk = 0; kk < 4; kk++) {
        fW2[kk][0] = pW2[((w * 4 + kk) * 2 + 0) * 64 + lane];
        fW2[kk][1] = pW2[((w * 4 + kk) * 2 + 1) * 64 + lane];
    }
    float rb1[2] = { b1[w * 32 + n15], b1[w * 32 + 16 + n15] };
    float rb2[2] = { b2[w * 32 + n15], b2[w * 32 + 16 + n15] };
    const int ntile = N_EDGES / 64;   // 9375 exact
    for (int tile = blockIdx.x; tile < ntile; tile += gridDim.x) {
        int row0 = tile * 64;
        if (tid < 64) sPos[tid] = pos_of[row0 + tid];
        if (tid >= 64 && tid < 192) {
            int t2 = tid - 64;
            int r = t2 >> 1, c4 = (t2 & 1) * 4;
            float4 v = *(const float4*)&attr[(long)(row0 + r) * ED + c4];
            ushort4 o;
            o.x = f2bf(v.x); o.y = f2bf(v.y); o.z = f2bf(v.z); o.w = f2bf(v.w);
            *(ushort4*)&sA[r * 40 + c4] = o;
        } else if (tid >= 192) {
            int idx = tid - 192;   // zero-fill k=8..31 : 64 rows * 3 chunks of 8
            for (; idx < 192; idx += 64) {
                int r = idx / 3, c8 = 8 + (idx % 3) * 8;
                *(uint4*)&sA[r * 40 + c8] = make_uint4(0, 0, 0, 0);
            }
        }
        __syncthreads();
        // GEMM1 (K=32, one step)
        f32x4 acc[4][2];
        #pragma unroll
        for (int s = 0; s < 4; s++) { acc[s][0] = (f32x4){0,0,0,0}; acc[s][1] = (f32x4){0,0,0,0}; }
        #pragma unroll
        for (int s = 0; s < 4; s++) {
            short8 a = *(const short8*)&sA[(s * 16 + n15) * 40 + quad * 8];
            acc[s][0] = __builtin_amdgcn_mfma_f32_16x16x32_bf16(a, fW1[0], acc[s][0], 0, 0, 0);
            acc[s][1] = __builtin_amdgcn_mfma_f32_16x16x32_bf16(a, fW1[1], acc[s][1], 0, 0, 0);
        }
        #pragma unroll
        for (int s = 0; s < 4; s++)
            #pragma unroll
            for (int nt = 0; nt < 2; nt++) {
                int col = w * 32 + nt * 16 + n15;
                #pragma unroll
                for (int reg = 0; reg < 4; reg++)
                    sH[(s * 16 + quad * 4 + reg) * 136 + col] =
                        f2bf(fmaxf(acc[s][nt][reg] + rb1[nt], 0.0f));
            }
        __syncthreads();
        // GEMM2 (K=128)
        #pragma unroll
        for (int s = 0; s < 4; s++) { acc[s][0] = (f32x4){0,0,0,0}; acc[s][1] = (f32x4){0,0,0,0}; }
        #pragma unroll
        for (int kk = 0; kk < 4; kk++) {
            #pragma unroll
            for (int s = 0; s < 4; s++) {
                short8 a = *(const short8*)&sH[(s * 16 + n15) * 136 + kk * 32 + quad * 8];
                acc[s][0] = __builtin_amdgcn_mfma_f32_16x16x32_bf16(a, fW2[kk][0], acc[s][0], 0, 0, 0);
                acc[s][1] = __builtin_amdgcn_mfma_f32_16x16x32_bf16(a, fW2[kk][1], acc[s][1], 0, 0, 0);
            }
        }
        #pragma unroll
        for (int s = 0; s < 4; s++)
            #pragma unroll
            for (int nt = 0; nt < 2; nt++) {
                int col = w * 32 + nt * 16 + n15;
                #pragma unroll
                for (int reg = 0; reg < 4; reg++) {
                    long r = sPos[s * 16 + quad * 4 + reg];
                    e_perm[r * H + col] = f2bf(acc[s][nt][reg] + rb2[nt]);
                }
            }
        __syncthreads();
    }
}

// ---- aggregate: xs[n] = x[n] + sum relu(x[src]+e); e read is SEQUENTIAL ---
// one wave per node, 12 VGPRs, no LDS -> high occupancy for latency hiding
__global__ __launch_bounds__(256) void aggregate_kernel(
    const int* __restrict__ src_list,
    const int* __restrict__ chunk_scan, const int* __restrict__ bsum_scan,
    const u16* __restrict__ e_perm,
    const u16* __restrict__ x,
    u16* __restrict__ xs_out)
{
    int wave = threadIdx.x >> 6;
    int lane = threadIdx.x & 63;
    int fo = lane * 2;
    const int ngroups = N_NODES / 4;   // 25000
    for (int g = blockIdx.x; g < ngroups; g += gridDim.x) {
        int n = g * 4 + wave;
        int beg = chunk_scan[n]     + bsum_scan[n >> 10];
        int end = chunk_scan[n + 1] + bsum_scan[(n + 1) >> 10];
        float a0 = 0.0f, a1 = 0.0f;
        for (int j0 = beg; j0 < end; j0 += 64) {
            int m = min(64, end - j0);
            int sv = (lane < m) ? src_list[j0 + lane] : 0;
            for (int j = 0; j < m; j++) {
                int src = __shfl(sv, j);                      // v_readlane
                u32 xv = *(const u32*)&x[(long)src * H + fo];
                u32 ev = *(const u32*)&e_perm[(long)(j0 + j) * H + fo];
                a0 += fmaxf(bf2f(xv & 0xffff) + bf2f(ev & 0xffff), 0.0f);
                a1 += fmaxf(bf2f(xv >> 16)    + bf2f(ev >> 16),    0.0f);
            }
        }
        u32 xself = *(const u32*)&x[(long)n * H + fo];
        float o0 = bf2f(xself & 0xffff) + a0;
        float o1 = bf2f(xself >> 16)    + a1;
        *(u32*)&xs_out[(long)n * H + fo] = (u32)f2bf(o0) | ((u32)f2bf(o1) << 16);
    }
}

// ---------------- conv MLP (MFMA both layers): bf16 in/out -----------------
__global__ __launch_bounds__(256) void conv_mlp_mfma(
    const u16* __restrict__ xs,
    const short8* __restrict__ pW1, const float* __restrict__ b1,
    const short8* __restrict__ pW2, const float* __restrict__ b2,
    u16* __restrict__ x_out)
{
    __shared__ u16 sA[64 * 136];
    __shared__ u16 sH[64 * 136];
    int tid = threadIdx.x;
    int w = tid >> 6, lane = tid & 63, quad = lane >> 4, n15 = lane & 15;
    short8 fW1[4][2], fW2[4][2];
    #pragma unroll
    for (int kk = 0; kk < 4; kk++) {
        fW1[kk][0] = pW1[((w * 4 + kk) * 2 + 0) * 64 + lane];
        fW1[kk][1] = pW1[((w * 4 + kk) * 2 + 1) * 64 + lane];
        fW2[kk][0] = pW2[((w * 4 + kk) * 2 + 0) * 64 + lane];
        fW2[kk][1] = pW2[((w * 4 + kk) * 2 + 1) * 64 + lane];
    }
    float rb1[2] = { b1[w * 32 + n15], b1[w * 32 + 16 + n15] };
    float rb2[2] = { b2[w * 32 + n15], b2[w * 32 + 16 + n15] };
    const int ntile = (N_NODES + 63) / 64;
    for (int tile = blockIdx.x; tile < ntile; tile += gridDim.x) {
        int row0 = tile * 64;
        for (int idx = tid; idx < 64 * 16; idx += 256) {
            int r = idx >> 4, c8 = (idx & 15) << 3;
            int n = row0 + r;
            uint4 v = make_uint4(0, 0, 0, 0);
            if (n < N_NODES) v = *(const uint4*)&xs[(long)n * H + c8];
            *(uint4*)&sA[r * 136 + c8] = v;
        }
        __syncthreads();
        f32x4 acc[4][2];
        #pragma unroll
        for (int s = 0; s < 4; s++) { acc[s][0] = (f32x4){0,0,0,0}; acc[s][1] = (f32x4){0,0,0,0}; }
        #pragma unroll
        for (int kk = 0; kk < 4; kk++) {
            #pragma unroll
            for (int s = 0; s < 4; s++) {
                short8 a = *(const short8*)&sA[(s * 16 + n15) * 136 + kk * 32 + quad * 8];
                acc[s][0] = __builtin_amdgcn_mfma_f32_16x16x32_bf16(a, fW1[kk][0], acc[s][0], 0, 0, 0);
                acc[s][1] = __builtin_amdgcn_mfma_f32_16x16x32_bf16(a, fW1[kk][1], acc[s][1], 0, 0, 0);
            }
        }
        #pragma unroll
        for (int s = 0; s < 4; s++)
            #pragma unroll
            for (int nt = 0; nt < 2; nt++) {
                int col = w * 32 + nt * 16 + n15;
                #pragma unroll
                for (int reg = 0; reg < 4; reg++)
                    sH[(s * 16 + quad * 4 + reg) * 136 + col] =
                        f2bf(fmaxf(acc[s][nt][reg] + rb1[nt], 0.0f));
            }
        __syncthreads();
        #pragma unroll
        for (int s = 0; s < 4; s++) { acc[s][0] = (f32x4){0,0,0,0}; acc[s][1] = (f32x4){0,0,0,0}; }
        #pragma unroll
        for (int kk = 0; kk < 4; kk++) {
            #pragma unroll
            for (int s = 0; s < 4; s++) {
                short8 a = *(const short8*)&sH[(s * 16 + n15) * 136 + kk * 32 + quad * 8];
                acc[s][0] = __builtin_amdgcn_mfma_f32_16x16x32_bf16(a, fW2[kk][0], acc[s][0], 0, 0, 0);
                acc[s][1] = __builtin_amdgcn_mfma_f32_16x16x32_bf16(a, fW2[kk][1], acc[s][1], 0, 0, 0);
            }
        }
        #pragma unroll
        for (int s = 0; s < 4; s++)
            #pragma unroll
            for (int nt = 0; nt < 2; nt++) {
                int col = w * 32 + nt * 16 + n15;
                #pragma unroll
                for (int reg = 0; reg < 4; reg++) {
                    int n = row0 + s * 16 + quad * 4 + reg;
                    if (n < N_NODES)
                        x_out[(long)n * H + col] = f2bf(fmaxf(acc[s][nt][reg] + rb2[nt], 0.0f));
                }
            }
        __syncthreads();
    }
}

// ---------------- mean-pool (sorted batch, segment flush) ------------------
__global__ __launch_bounds__(128) void pool_kernel(
    const u16* __restrict__ x, const int* __restrict__ batch,
    float* __restrict__ sums, float* __restrict__ cnt)
{
    int j = threadIdx.x;
    const int nper = (N_NODES + gridDim.x - 1) / gridDim.x;
    int n0 = blockIdx.x * nper;
    int n1 = min(n0 + nper, N_NODES);
    if (n0 >= n1) return;
    int cur = -1;
    float acc = 0.0f, cacc = 0.0f;
    for (int n = n0; n < n1; n++) {
        int b = batch[n];
        if (b != cur) {
            if (cur >= 0) {
                atomicAdd(&sums[cur * H + j], acc);
                if (j == 0) atomicAdd(&cnt[cur], cacc);
            }
            acc = 0.0f; cacc = 0.0f; cur = b;
        }
        acc += bf2f(x[(long)n * H + j]);
        cacc += 1.0f;
    }
    if (cur >= 0) {
        atomicAdd(&sums[cur * H + j], acc);
        if (j == 0) atomicAdd(&cnt[cur], cacc);
    }
}

// ---------------- regressor ------------------------------------------------
__global__ __launch_bounds__(128) void regressor_kernel(
    const float* __restrict__ sums, const float* __restrict__ cnt,
    const float* __restrict__ depth,
    const float* __restrict__ w1, const float* __restrict__ b1,
    const float* __restrict__ w2, const float* __restrict__ b2,
    float* __restrict__ out)
{
    __shared__ float s_mean[H];
    __shared__ float s_red[2];
    int b = blockIdx.x;
    int j = threadIdx.x;
    float c = fmaxf(cnt[b], 1.0f);
    s_mean[j] = sums[b * H + j] / c;
    __syncthreads();
    float h = b1[j];
    #pragma unroll 8
    for (int k = 0; k < H; k++) h += s_mean[k] * w1[k * H + j];
    h += depth[b] * w1[H * H + j];
    h = fmaxf(h, 0.0f);
    float p = h * w2[j];
    #pragma unroll
    for (int off = 32; off >= 1; off >>= 1) p += __shfl_down(p, off, 64);
    if ((j & 63) == 0) s_red[j >> 6] = p;
    __syncthreads();
    if (j == 0) out[b] = s_red[0] + s_red[1] + b2[0];
}

extern "C" void kernel_launch(void* const* d_in, const int* in_sizes, int n_in,
                              void* d_out, int out_size, void* d_ws, size_t ws_size,
                              hipStream_t stream)
{
    const int*   ids   = (const int*)  d_in[0];
    const int*   eidx  = (const int*)  d_in[1];
    const float* eattr = (const float*)d_in[2];
    const int*   batch = (const int*)  d_in[3];
    const float* depth = (const float*)d_in[4];
    const float* id_w1 = (const float*)d_in[5];
    const float* id_b1 = (const float*)d_in[6];
    const float* id_w2 = (const float*)d_in[7];
    const float* id_b2 = (const float*)d_in[8];
    const float* ed_w1 = (const float*)d_in[9];
    const float* ed_b1 = (const float*)d_in[10];
    const float* ed_w2 = (const float*)d_in[11];
    const float* ed_b2 = (const float*)d_in[12];
    const float* c1_w1 = (const float*)d_in[13];
    const float* c1_b1 = (const float*)d_in[14];
    const float* c1_w2 = (const float*)d_in[15];
    const float* c1_b2 = (const float*)d_in[16];
    const float* c2_w1 = (const float*)d_in[17];
    const float* c2_b1 = (const float*)d_in[18];
    const float* c2_w2 = (const float*)d_in[19];
    const float* c2_b2 = (const float*)d_in[20];
    const float* rg_w1 = (const float*)d_in[21];
    const float* rg_b1 = (const float*)d_in[22];
    const float* rg_w2 = (const float*)d_in[23];
    const float* rg_b2 = (const float*)d_in[24];

    char* ws = (char*)d_ws;
    u16*   e_buf    = (u16*)  (ws);                      // 153,600,000 B (CSR order)
    u16*   x_buf    = (u16*)  (ws + 153600000);          //  25,600,000 B
    u16*   xs_buf   = (u16*)  (ws + 179200000);          //  25,600,000 B
    float* sums_buf = (float*)(ws + 204800000);          //     262,144 B
    float* cnt_buf  = (float*)(ws + 205062144);          //       2,048 B
    int*   counts   = (int*)  (ws + 205064192);          //     401,408 B
    int*   chunk_sc = (int*)  (ws + 205465600);          //     401,408 B
    int*   bsum_raw = (int*)  (ws + 205867008);          //         512 B
    int*   bsum_sc  = (int*)  (ws + 205867520);          //         512 B
    int*   src_list = (int*)  (ws + 205868032);          //   2,400,000 B
    int*   pos_of   = (int*)  (ws + 208268032);          //   2,400,000 B
    short8* ed_w1p  = (short8*)(ws + 210668032);         //       8,192 B
    short8* ed_w2p  = (short8*)(ws + 210676224);         //      32,768 B
    short8* c1_w1p  = (short8*)(ws + 210708992);
    short8* c1_w2p  = (short8*)(ws + 210741760);
    short8* c2_w1p  = (short8*)(ws + 210774528);
    short8* c2_w2p  = (short8*)(ws + 210807296);
    short8* id_w2p  = (short8*)(ws + 210840064);

    // weight packs (tiny)
    pack_weights_kernel<<<2, 256, 0, stream>>>(ed_w1, ED, 1, ed_w1p);
    pack_weights_kernel<<<8, 256, 0, stream>>>(ed_w2, H, 4, ed_w2p);
    pack_weights_kernel<<<8, 256, 0, stream>>>(c1_w1, H, 4, c1_w1p);
    pack_weights_kernel<<<8, 256, 0, stream>>>(c1_w2, H, 4, c1_w2p);
    pack_weights_kernel<<<8, 256, 0, stream>>>(c2_w1, H, 4, c2_w1p);
    pack_weights_kernel<<<8, 256, 0, stream>>>(c2_w2, H, 4, c2_w2p);
    pack_weights_kernel<<<8, 256, 0, stream>>>(id_w2, H, 4, id_w2p);

    // CSR build first (edge_mlp needs pos_of)
    hipMemsetAsync(counts, 0, 401408, stream);
    hist_kernel <<<(N_EDGES + 255) / 256, 256, 0, stream>>>(eidx, counts);
    scan1_kernel<<<N_CHUNKS, SCAN_CHUNK, 0, stream>>>(counts, chunk_sc, bsum_raw);
    scan2_kernel<<<1, 128, 0, stream>>>(bsum_raw, bsum_sc);
    fill_kernel <<<(N_EDGES + 255) / 256, 256, 0, stream>>>(eidx, chunk_sc, bsum_sc,
                                                            counts, src_list, pos_of);

    // front-end
    node_mlp_mfma<<<768, 256, 0, stream>>>(ids, id_w1, id_b1, id_w2p, id_b2, x_buf);
    edge_mlp_mfma<<<2048, 256, 0, stream>>>(eattr, pos_of, ed_w1p, ed_b1, ed_w2p, ed_b2, e_buf);

    // conv 1
    aggregate_kernel<<<8192, 256, 0, stream>>>(src_list, chunk_sc, bsum_sc, e_buf, x_buf, xs_buf);
    conv_mlp_mfma<<<1563, 256, 0, stream>>>(xs_buf, c1_w1p, c1_b1, c1_w2p, c1_b2, x_buf);

    // conv 2
    aggregate_kernel<<<8192, 256, 0, stream>>>(src_list, chunk_sc, bsum_sc, e_buf, x_buf, xs_buf);
    conv_mlp_mfma<<<1563, 256, 0, stream>>>(xs_buf, c2_w1p, c2_b1, c2_w2p, c2_b2, x_buf);

    // pooling + regressor
    hipMemsetAsync(sums_buf, 0, (size_t)(NB * H + NB) * 4, stream);
    pool_kernel<<<512, 128, 0, stream>>>(x_buf, batch, sums_buf, cnt_buf);
    regressor_kernel<<<NB, 128, 0, stream>>>(sums_buf, cnt_buf, depth,
                                             rg_w1, rg_b1, rg_w2, rg_b2, (float*)d_out);
}

// Round 6
// 438.056 us; speedup vs baseline: 1.5872x; 1.1572x over previous
//
#include <hip/hip_runtime.h>
#include <hip/hip_bf16.h>

#define N_NODES 100000
#define N_EDGES 600000
#define NB      512
#define H       128
#define ED      8
#define SCAN_CHUNK 1024
#define N_CHUNKS   98   // 98*1024 = 100352 >= N_NODES+1

typedef __attribute__((ext_vector_type(8))) short short8;
typedef __attribute__((ext_vector_type(4))) float f32x4;
typedef unsigned short u16;
typedef unsigned int   u32;

static __device__ __forceinline__ u16 f2bf(float f) {
    u32 u = __float_as_uint(f);
    u32 r = u + 0x7fffu + ((u >> 16) & 1u);
    return (u16)(r >> 16);
}
static __device__ __forceinline__ float bf2f(u32 h) {
    return __uint_as_float(h << 16);
}

// ---- weight pack (ALL matrices in one launch) -----------------------------
// layout per matrix: slot = ((w*kkmax + kk)*2 + nt)*64 + lane
// ranges: m0 ed_w1 (kkmax=1, K=8) slots [0,512); m1..m6 (kkmax=4, K=128) 2048 each
__global__ __launch_bounds__(256) void pack_all_kernel(
    const float* __restrict__ W0, const float* __restrict__ W1,
    const float* __restrict__ W2, const float* __restrict__ W3,
    const float* __restrict__ W4, const float* __restrict__ W5,
    const float* __restrict__ W6,
    short8* __restrict__ O0, short8* __restrict__ O1,
    short8* __restrict__ O2, short8* __restrict__ O3,
    short8* __restrict__ O4, short8* __restrict__ O5,
    short8* __restrict__ O6)
{
    int gid = blockIdx.x * 256 + threadIdx.x;
    const int total = 512 + 6 * 2048;
    if (gid >= total) return;
    const float* W; short8* O; int Krows, kkmax, slot;
    if (gid < 512) { W = W0; O = O0; Krows = ED; kkmax = 1; slot = gid; }
    else {
        int m = (gid - 512) / 2048;
        slot = (gid - 512) % 2048;
        Krows = H; kkmax = 4;
        switch (m) {
            case 0: W = W1; O = O1; break;
            case 1: W = W2; O = O2; break;
            case 2: W = W3; O = O3; break;
            case 3: W = W4; O = O4; break;
            case 4: W = W5; O = O5; break;
            default: W = W6; O = O6; break;
        }
    }
    int lane = slot & 63;
    int t = slot >> 6;
    int nt = t & 1; t >>= 1;
    int kk = t % kkmax;
    int w  = t / kkmax;
    int quad = lane >> 4, n15 = lane & 15;
    int n = w * 32 + nt * 16 + n15;
    short8 v;
    #pragma unroll
    for (int j = 0; j < 8; j++) {
        int k = kk * 32 + quad * 8 + j;
        v[j] = (k < Krows) ? (short)f2bf(W[k * H + n]) : (short)0;
    }
    O[slot] = v;
}

// ---------------- CSR build ------------------------------------------------
__global__ __launch_bounds__(256) void hist_kernel(
    const int* __restrict__ edge_index, int* __restrict__ counts)
{
    int e = blockIdx.x * 256 + threadIdx.x;
    if (e < N_EDGES) atomicAdd(&counts[edge_index[N_EDGES + e]], 1);
}

__global__ __launch_bounds__(SCAN_CHUNK) void scan1_kernel(
    const int* __restrict__ counts, int* __restrict__ chunk_scan,
    int* __restrict__ bsum_raw)
{
    __shared__ int s[SCAN_CHUNK];
    int tid = threadIdx.x;
    int gid = blockIdx.x * SCAN_CHUNK + tid;
    int v = counts[gid];
    s[tid] = v;
    __syncthreads();
    #pragma unroll
    for (int off = 1; off < SCAN_CHUNK; off <<= 1) {
        int t = (tid >= off) ? s[tid - off] : 0;
        __syncthreads();
        s[tid] += t;
        __syncthreads();
    }
    chunk_scan[gid] = s[tid] - v;
    if (tid == SCAN_CHUNK - 1) bsum_raw[blockIdx.x] = s[tid];
}

__global__ __launch_bounds__(128) void scan2_kernel(
    const int* __restrict__ bsum_raw, int* __restrict__ bsum_scan)
{
    __shared__ int s[128];
    int tid = threadIdx.x;
    int v = (tid < N_CHUNKS) ? bsum_raw[tid] : 0;
    s[tid] = v;
    __syncthreads();
    #pragma unroll
    for (int off = 1; off < 128; off <<= 1) {
        int t = (tid >= off) ? s[tid - off] : 0;
        __syncthreads();
        s[tid] += t;
        __syncthreads();
    }
    bsum_scan[tid] = s[tid] - v;
}

// fill: src_list[pos]=src (CSR order), pos_of[e]=pos (for edge_mlp scatter)
__global__ __launch_bounds__(256) void fill_kernel(
    const int* __restrict__ edge_index,
    const int* __restrict__ chunk_scan, const int* __restrict__ bsum_scan,
    int* __restrict__ counts, int* __restrict__ src_list,
    int* __restrict__ pos_of)
{
    int e = blockIdx.x * 256 + threadIdx.x;
    if (e >= N_EDGES) return;
    int src = edge_index[e];
    int dst = edge_index[N_EDGES + e];
    int slot = atomicAdd(&counts[dst], -1) - 1;
    int pos = chunk_scan[dst] + bsum_scan[dst >> 10] + slot;
    src_list[pos] = src;
    pos_of[e] = pos;
}

// ---------------- node MLP (MFMA layer2): x bf16 [N,H] ---------------------
__global__ __launch_bounds__(256) void node_mlp_mfma(
    const int* __restrict__ ids,
    const float* __restrict__ w1, const float* __restrict__ b1,
    const short8* __restrict__ pW2, const float* __restrict__ b2,
    u16* __restrict__ x_out)
{
    __shared__ u16 sH[64 * 136];
    __shared__ float s_x0[64];
    int tid = threadIdx.x;
    int w = tid >> 6, lane = tid & 63, quad = lane >> 4, n15 = lane & 15;
    short8 fW2[4][2];
    #pragma unroll
    for (int kk = 0; kk < 4; kk++) {
        fW2[kk][0] = pW2[((w * 4 + kk) * 2 + 0) * 64 + lane];
        fW2[kk][1] = pW2[((w * 4 + kk) * 2 + 1) * 64 + lane];
    }
    float rb2[2] = { b2[w * 32 + n15], b2[w * 32 + 16 + n15] };
    float w1c = w1[tid & 127], b1c = b1[tid & 127];
    const int ntile = (N_NODES + 63) / 64;
    for (int tile = blockIdx.x; tile < ntile; tile += gridDim.x) {
        int row0 = tile * 64;
        if (tid < 64) {
            int n = row0 + tid;
            float x0 = (n < N_NODES) ? (float)ids[n] / 281474976710655.0f : 0.0f;
            s_x0[tid] = fminf(fmaxf(x0, 0.0f), 1.0f);
        }
        __syncthreads();
        int half = tid >> 7, c = tid & 127;
        #pragma unroll 8
        for (int rr = 0; rr < 32; rr++) {
            int r = half + rr * 2;
            sH[r * 136 + c] = f2bf(fmaxf(s_x0[r] * w1c + b1c, 0.0f));
        }
        __syncthreads();
        f32x4 acc[4][2];
        #pragma unroll
        for (int s = 0; s < 4; s++) { acc[s][0] = (f32x4){0,0,0,0}; acc[s][1] = (f32x4){0,0,0,0}; }
        #pragma unroll
        for (int kk = 0; kk < 4; kk++) {
            #pragma unroll
            for (int s = 0; s < 4; s++) {
                short8 a = *(const short8*)&sH[(s * 16 + n15) * 136 + kk * 32 + quad * 8];
                acc[s][0] = __builtin_amdgcn_mfma_f32_16x16x32_bf16(a, fW2[kk][0], acc[s][0], 0, 0, 0);
                acc[s][1] = __builtin_amdgcn_mfma_f32_16x16x32_bf16(a, fW2[kk][1], acc[s][1], 0, 0, 0);
            }
        }
        #pragma unroll
        for (int s = 0; s < 4; s++)
            #pragma unroll
            for (int nt = 0; nt < 2; nt++) {
                int col = w * 32 + nt * 16 + n15;
                #pragma unroll
                for (int reg = 0; reg < 4; reg++) {
                    int n = row0 + s * 16 + quad * 4 + reg;
                    if (n < N_NODES)
                        x_out[(long)n * H + col] = f2bf(acc[s][nt][reg] + rb2[nt]);
                }
            }
        __syncthreads();
    }
}

// ---------------- edge MLP (MFMA): writes e in CSR-permuted order ----------
__global__ __launch_bounds__(256) void edge_mlp_mfma(
    const float* __restrict__ attr,
    const int* __restrict__ pos_of,
    const short8* __restrict__ pW1, const float* __restrict__ b1,
    const short8* __restrict__ pW2, const float* __restrict__ b2,
    u16* __restrict__ e_perm)
{
    __shared__ u16 sA[64 * 40];
    __shared__ u16 sH[64 * 136];
    __shared__ int sPos[64];
    int tid = threadIdx.x;
    int w = tid >> 6, lane = tid & 63, quad = lane >> 4, n15 = lane & 15;
    short8 fW1[2];
    fW1[0] = pW1[(w * 2 + 0) * 64 + lane];
    fW1[1] = pW1[(w * 2 + 1) * 64 + lane];
    short8 fW2[4][2];
    #pragma unroll
    for (int kk = 0; kk < 4; kk++) {
        fW2[kk][0] = pW2[((w * 4 + kk) * 2 + 0) * 64 + lane];
        fW2[kk][1] = pW2[((w * 4 + kk) * 2 + 1) * 64 + lane];
    }
    float rb1[2] = { b1[w * 32 + n15], b1[w * 32 + 16 + n15] };
    float rb2[2] = { b2[w * 32 + n15], b2[w * 32 + 16 + n15] };
    const int ntile = N_EDGES / 64;   // 9375 exact
    for (int tile = blockIdx.x; tile < ntile; tile += gridDim.x) {
        int row0 = tile * 64;
        if (tid < 64) sPos[tid] = pos_of[row0 + tid];
        if (tid >= 64 && tid < 192) {
            int t2 = tid - 64;
            int r = t2 >> 1, c4 = (t2 & 1) * 4;
            float4 v = *(const float4*)&attr[(long)(row0 + r) * ED + c4];
            ushort4 o;
            o.x = f2bf(v.x); o.y = f2bf(v.y); o.z = f2bf(v.z); o.w = f2bf(v.w);
            *(ushort4*)&sA[r * 40 + c4] = o;
        } else if (tid >= 192) {
            int idx = tid - 192;   // zero-fill k=8..31 : 64 rows * 3 chunks of 8
            for (; idx < 192; idx += 64) {
                int r = idx / 3, c8 = 8 + (idx % 3) * 8;
                *(uint4*)&sA[r * 40 + c8] = make_uint4(0, 0, 0, 0);
            }
        }
        __syncthreads();
        // GEMM1 (K=32, one step)
        f32x4 acc[4][2];
        #pragma unroll
        for (int s = 0; s < 4; s++) { acc[s][0] = (f32x4){0,0,0,0}; acc[s][1] = (f32x4){0,0,0,0}; }
        #pragma unroll
        for (int s = 0; s < 4; s++) {
            short8 a = *(const short8*)&sA[(s * 16 + n15) * 40 + quad * 8];
            acc[s][0] = __builtin_amdgcn_mfma_f32_16x16x32_bf16(a, fW1[0], acc[s][0], 0, 0, 0);
            acc[s][1] = __builtin_amdgcn_mfma_f32_16x16x32_bf16(a, fW1[1], acc[s][1], 0, 0, 0);
        }
        #pragma unroll
        for (int s = 0; s < 4; s++)
            #pragma unroll
            for (int nt = 0; nt < 2; nt++) {
                int col = w * 32 + nt * 16 + n15;
                #pragma unroll
                for (int reg = 0; reg < 4; reg++)
                    sH[(s * 16 + quad * 4 + reg) * 136 + col] =
                        f2bf(fmaxf(acc[s][nt][reg] + rb1[nt], 0.0f));
            }
        __syncthreads();
        // GEMM2 (K=128)
        #pragma unroll
        for (int s = 0; s < 4; s++) { acc[s][0] = (f32x4){0,0,0,0}; acc[s][1] = (f32x4){0,0,0,0}; }
        #pragma unroll
        for (int kk = 0; kk < 4; kk++) {
            #pragma unroll
            for (int s = 0; s < 4; s++) {
                short8 a = *(const short8*)&sH[(s * 16 + n15) * 136 + kk * 32 + quad * 8];
                acc[s][0] = __builtin_amdgcn_mfma_f32_16x16x32_bf16(a, fW2[kk][0], acc[s][0], 0, 0, 0);
                acc[s][1] = __builtin_amdgcn_mfma_f32_16x16x32_bf16(a, fW2[kk][1], acc[s][1], 0, 0, 0);
            }
        }
        #pragma unroll
        for (int s = 0; s < 4; s++)
            #pragma unroll
            for (int nt = 0; nt < 2; nt++) {
                int col = w * 32 + nt * 16 + n15;
                #pragma unroll
                for (int reg = 0; reg < 4; reg++) {
                    long r = sPos[s * 16 + quad * 4 + reg];
                    e_perm[r * H + col] = f2bf(acc[s][nt][reg] + rb2[nt]);
                }
            }
        __syncthreads();
    }
}

// ---- aggregate: xs[n] = x[n] + sum relu(x[src]+e); e read is SEQUENTIAL ---
__global__ __launch_bounds__(256) void aggregate_kernel(
    const int* __restrict__ src_list,
    const int* __restrict__ chunk_scan, const int* __restrict__ bsum_scan,
    const u16* __restrict__ e_perm,
    const u16* __restrict__ x,
    u16* __restrict__ xs_out)
{
    int wave = threadIdx.x >> 6;
    int lane = threadIdx.x & 63;
    int fo = lane * 2;
    const int ngroups = N_NODES / 4;   // 25000
    for (int g = blockIdx.x; g < ngroups; g += gridDim.x) {
        int n = g * 4 + wave;
        int beg = chunk_scan[n]     + bsum_scan[n >> 10];
        int end = chunk_scan[n + 1] + bsum_scan[(n + 1) >> 10];
        float a0 = 0.0f, a1 = 0.0f;
        for (int j0 = beg; j0 < end; j0 += 64) {
            int m = min(64, end - j0);
            int sv = (lane < m) ? src_list[j0 + lane] : 0;
            for (int j = 0; j < m; j++) {
                int src = __shfl(sv, j);                      // v_readlane
                u32 xv = *(const u32*)&x[(long)src * H + fo];
                u32 ev = *(const u32*)&e_perm[(long)(j0 + j) * H + fo];
                a0 += fmaxf(bf2f(xv & 0xffff) + bf2f(ev & 0xffff), 0.0f);
                a1 += fmaxf(bf2f(xv >> 16)    + bf2f(ev >> 16),    0.0f);
            }
        }
        u32 xself = *(const u32*)&x[(long)n * H + fo];
        float o0 = bf2f(xself & 0xffff) + a0;
        float o1 = bf2f(xself >> 16)    + a1;
        *(u32*)&xs_out[(long)n * H + fo] = (u32)f2bf(o0) | ((u32)f2bf(o1) << 16);
    }
}

// ---------------- conv MLP (MFMA both layers): bf16 in/out -----------------
__global__ __launch_bounds__(256) void conv_mlp_mfma(
    const u16* __restrict__ xs,
    const short8* __restrict__ pW1, const float* __restrict__ b1,
    const short8* __restrict__ pW2, const float* __restrict__ b2,
    u16* __restrict__ x_out)
{
    __shared__ u16 sA[64 * 136];
    __shared__ u16 sH[64 * 136];
    int tid = threadIdx.x;
    int w = tid >> 6, lane = tid & 63, quad = lane >> 4, n15 = lane & 15;
    short8 fW1[4][2], fW2[4][2];
    #pragma unroll
    for (int kk = 0; kk < 4; kk++) {
        fW1[kk][0] = pW1[((w * 4 + kk) * 2 + 0) * 64 + lane];
        fW1[kk][1] = pW1[((w * 4 + kk) * 2 + 1) * 64 + lane];
        fW2[kk][0] = pW2[((w * 4 + kk) * 2 + 0) * 64 + lane];
        fW2[kk][1] = pW2[((w * 4 + kk) * 2 + 1) * 64 + lane];
    }
    float rb1[2] = { b1[w * 32 + n15], b1[w * 32 + 16 + n15] };
    float rb2[2] = { b2[w * 32 + n15], b2[w * 32 + 16 + n15] };
    const int ntile = (N_NODES + 63) / 64;
    for (int tile = blockIdx.x; tile < ntile; tile += gridDim.x) {
        int row0 = tile * 64;
        for (int idx = tid; idx < 64 * 16; idx += 256) {
            int r = idx >> 4, c8 = (idx & 15) << 3;
            int n = row0 + r;
            uint4 v = make_uint4(0, 0, 0, 0);
            if (n < N_NODES) v = *(const uint4*)&xs[(long)n * H + c8];
            *(uint4*)&sA[r * 136 + c8] = v;
        }
        __syncthreads();
        f32x4 acc[4][2];
        #pragma unroll
        for (int s = 0; s < 4; s++) { acc[s][0] = (f32x4){0,0,0,0}; acc[s][1] = (f32x4){0,0,0,0}; }
        #pragma unroll
        for (int kk = 0; kk < 4; kk++) {
            #pragma unroll
            for (int s = 0; s < 4; s++) {
                short8 a = *(const short8*)&sA[(s * 16 + n15) * 136 + kk * 32 + quad * 8];
                acc[s][0] = __builtin_amdgcn_mfma_f32_16x16x32_bf16(a, fW1[kk][0], acc[s][0], 0, 0, 0);
                acc[s][1] = __builtin_amdgcn_mfma_f32_16x16x32_bf16(a, fW1[kk][1], acc[s][1], 0, 0, 0);
            }
        }
        #pragma unroll
        for (int s = 0; s < 4; s++)
            #pragma unroll
            for (int nt = 0; nt < 2; nt++) {
                int col = w * 32 + nt * 16 + n15;
                #pragma unroll
                for (int reg = 0; reg < 4; reg++)
                    sH[(s * 16 + quad * 4 + reg) * 136 + col] =
                        f2bf(fmaxf(acc[s][nt][reg] + rb1[nt], 0.0f));
            }
        __syncthreads();
        #pragma unroll
        for (int s = 0; s < 4; s++) { acc[s][0] = (f32x4){0,0,0,0}; acc[s][1] = (f32x4){0,0,0,0}; }
        #pragma unroll
        for (int kk = 0; kk < 4; kk++) {
            #pragma unroll
            for (int s = 0; s < 4; s++) {
                short8 a = *(const short8*)&sH[(s * 16 + n15) * 136 + kk * 32 + quad * 8];
                acc[s][0] = __builtin_amdgcn_mfma_f32_16x16x32_bf16(a, fW2[kk][0], acc[s][0], 0, 0, 0);
                acc[s][1] = __builtin_amdgcn_mfma_f32_16x16x32_bf16(a, fW2[kk][1], acc[s][1], 0, 0, 0);
            }
        }
        #pragma unroll
        for (int s = 0; s < 4; s++)
            #pragma unroll
            for (int nt = 0; nt < 2; nt++) {
                int col = w * 32 + nt * 16 + n15;
                #pragma unroll
                for (int reg = 0; reg < 4; reg++) {
                    int n = row0 + s * 16 + quad * 4 + reg;
                    if (n < N_NODES)
                        x_out[(long)n * H + col] = f2bf(fmaxf(acc[s][nt][reg] + rb2[nt], 0.0f));
                }
            }
        __syncthreads();
    }
}

// ---------------- mean-pool v2: vectorized, high-TLP, segment flush --------
// 4 subgroups of 64 lanes per block; lane handles 2 cols (u32); subgroup
// strides rows by 4 inside the block's window (sorted => flush-on-change ok)
__global__ __launch_bounds__(256) void pool_kernel(
    const u16* __restrict__ x, const int* __restrict__ batch,
    float* __restrict__ sums, float* __restrict__ cnt)
{
    int sg   = threadIdx.x >> 6;
    int lane = threadIdx.x & 63;
    int fo = lane * 2;
    const int nper = (N_NODES + gridDim.x - 1) / gridDim.x;
    int n0 = blockIdx.x * nper;
    int n1 = min(n0 + nper, N_NODES);
    int cur = -1;
    float a0 = 0.0f, a1 = 0.0f, c = 0.0f;
    for (int n = n0 + sg; n < n1; n += 4) {
        int b = batch[n];
        if (b != cur) {
            if (cur >= 0) {
                atomicAdd(&sums[cur * H + fo],     a0);
                atomicAdd(&sums[cur * H + fo + 1], a1);
                if (lane == 0) atomicAdd(&cnt[cur], c);
            }
            a0 = a1 = 0.0f; c = 0.0f; cur = b;
        }
        u32 xv = *(const u32*)&x[(long)n * H + fo];
        a0 += bf2f(xv & 0xffff);
        a1 += bf2f(xv >> 16);
        c += 1.0f;
    }
    if (cur >= 0) {
        atomicAdd(&sums[cur * H + fo],     a0);
        atomicAdd(&sums[cur * H + fo + 1], a1);
        if (lane == 0) atomicAdd(&cnt[cur], c);
    }
}

// ---------------- regressor ------------------------------------------------
__global__ __launch_bounds__(128) void regressor_kernel(
    const float* __restrict__ sums, const float* __restrict__ cnt,
    const float* __restrict__ depth,
    const float* __restrict__ w1, const float* __restrict__ b1,
    const float* __restrict__ w2, const float* __restrict__ b2,
    float* __restrict__ out)
{
    __shared__ float s_mean[H];
    __shared__ float s_red[2];
    int b = blockIdx.x;
    int j = threadIdx.x;
    float c = fmaxf(cnt[b], 1.0f);
    s_mean[j] = sums[b * H + j] / c;
    __syncthreads();
    float h = b1[j];
    #pragma unroll 8
    for (int k = 0; k < H; k++) h += s_mean[k] * w1[k * H + j];
    h += depth[b] * w1[H * H + j];
    h = fmaxf(h, 0.0f);
    float p = h * w2[j];
    #pragma unroll
    for (int off = 32; off >= 1; off >>= 1) p += __shfl_down(p, off, 64);
    if ((j & 63) == 0) s_red[j >> 6] = p;
    __syncthreads();
    if (j == 0) out[b] = s_red[0] + s_red[1] + b2[0];
}

extern "C" void kernel_launch(void* const* d_in, const int* in_sizes, int n_in,
                              void* d_out, int out_size, void* d_ws, size_t ws_size,
                              hipStream_t stream)
{
    const int*   ids   = (const int*)  d_in[0];
    const int*   eidx  = (const int*)  d_in[1];
    const float* eattr = (const float*)d_in[2];
    const int*   batch = (const int*)  d_in[3];
    const float* depth = (const float*)d_in[4];
    const float* id_w1 = (const float*)d_in[5];
    const float* id_b1 = (const float*)d_in[6];
    const float* id_w2 = (const float*)d_in[7];
    const float* id_b2 = (const float*)d_in[8];
    const float* ed_w1 = (const float*)d_in[9];
    const float* ed_b1 = (const float*)d_in[10];
    const float* ed_w2 = (const float*)d_in[11];
    const float* ed_b2 = (const float*)d_in[12];
    const float* c1_w1 = (const float*)d_in[13];
    const float* c1_b1 = (const float*)d_in[14];
    const float* c1_w2 = (const float*)d_in[15];
    const float* c1_b2 = (const float*)d_in[16];
    const float* c2_w1 = (const float*)d_in[17];
    const float* c2_b1 = (const float*)d_in[18];
    const float* c2_w2 = (const float*)d_in[19];
    const float* c2_b2 = (const float*)d_in[20];
    const float* rg_w1 = (const float*)d_in[21];
    const float* rg_b1 = (const float*)d_in[22];
    const float* rg_w2 = (const float*)d_in[23];
    const float* rg_b2 = (const float*)d_in[24];

    char* ws = (char*)d_ws;
    u16*   e_buf    = (u16*)  (ws);                      // 153,600,000 B (CSR order)
    u16*   x_buf    = (u16*)  (ws + 153600000);          //  25,600,000 B
    u16*   xs_buf   = (u16*)  (ws + 179200000);          //  25,600,000 B
    float* sums_buf = (float*)(ws + 204800000);          //     262,144 B
    float* cnt_buf  = (float*)(ws + 205062144);          //       2,048 B
    int*   counts   = (int*)  (ws + 205064192);          //     401,408 B
    int*   chunk_sc = (int*)  (ws + 205465600);          //     401,408 B
    int*   bsum_raw = (int*)  (ws + 205867008);          //         512 B
    int*   bsum_sc  = (int*)  (ws + 205867520);          //         512 B
    int*   src_list = (int*)  (ws + 205868032);          //   2,400,000 B
    int*   pos_of   = (int*)  (ws + 208268032);          //   2,400,000 B
    short8* ed_w1p  = (short8*)(ws + 210668032);         //       8,192 B
    short8* ed_w2p  = (short8*)(ws + 210676224);         //      32,768 B
    short8* c1_w1p  = (short8*)(ws + 210708992);
    short8* c1_w2p  = (short8*)(ws + 210741760);
    short8* c2_w1p  = (short8*)(ws + 210774528);
    short8* c2_w2p  = (short8*)(ws + 210807296);
    short8* id_w2p  = (short8*)(ws + 210840064);

    // all weight packs in one launch (512 + 6*2048 = 12800 threads)
    pack_all_kernel<<<50, 256, 0, stream>>>(
        ed_w1, ed_w2, c1_w1, c1_w2, c2_w1, c2_w2, id_w2,
        ed_w1p, ed_w2p, c1_w1p, c1_w2p, c2_w1p, c2_w2p, id_w2p);

    // CSR build first (edge_mlp needs pos_of)
    hipMemsetAsync(counts, 0, 401408, stream);
    hist_kernel <<<(N_EDGES + 255) / 256, 256, 0, stream>>>(eidx, counts);
    scan1_kernel<<<N_CHUNKS, SCAN_CHUNK, 0, stream>>>(counts, chunk_sc, bsum_raw);
    scan2_kernel<<<1, 128, 0, stream>>>(bsum_raw, bsum_sc);
    fill_kernel <<<(N_EDGES + 255) / 256, 256, 0, stream>>>(eidx, chunk_sc, bsum_sc,
                                                            counts, src_list, pos_of);

    // front-end
    node_mlp_mfma<<<768, 256, 0, stream>>>(ids, id_w1, id_b1, id_w2p, id_b2, x_buf);
    edge_mlp_mfma<<<2048, 256, 0, stream>>>(eattr, pos_of, ed_w1p, ed_b1, ed_w2p, ed_b2, e_buf);

    // conv 1
    aggregate_kernel<<<8192, 256, 0, stream>>>(src_list, chunk_sc, bsum_sc, e_buf, x_buf, xs_buf);
    conv_mlp_mfma<<<1563, 256, 0, stream>>>(xs_buf, c1_w1p, c1_b1, c1_w2p, c1_b2, x_buf);

    // conv 2
    aggregate_kernel<<<8192, 256, 0, stream>>>(src_list, chunk_sc, bsum_sc, e_buf, x_buf, xs_buf);
    conv_mlp_mfma<<<1563, 256, 0, stream>>>(xs_buf, c2_w1p, c2_b1, c2_w2p, c2_b2, x_buf);

    // pooling + regressor
    hipMemsetAsync(sums_buf, 0, (size_t)(NB * H + NB) * 4, stream);
    pool_kernel<<<2048, 256, 0, stream>>>(x_buf, batch, sums_buf, cnt_buf);
    regressor_kernel<<<NB, 128, 0, stream>>>(sums_buf, cnt_buf, depth,
                                             rg_w1, rg_b1, rg_w2, rg_b2, (float*)d_out);
}